// Round 11
// baseline (48.047 us; speedup 1.0000x reference)
//
#include <hip/hip_runtime.h>
#include <math.h>

// DRMM pipeline for MI355X (gfx950) — round 11: R10 + qn-from-LDS (kills the
// redundant per-block q-row global reads) + phase-2 W1 LDS bulk-stage.
// Phase 1: 1024 blocks x 256 thr; lane = one doc token; row streamed as 4
//   bursts of 8 float4 with forced A/B double-buffer (asm liveness pins);
//   q vectors staged once into LDS (lgkmcnt-decoupled from row vmcnt).
// Phase 2: MLP 30->128->64->32->1 + gate softmax + output. 512 blocks x 512 thr;
//   W1 (32KB) bulk-staged to LDS before the 128-iter layer-2 loop.
// B=32, D=16, L=512, Q=8, E=128, NB=30

#define BN_INV 0.99950037468777346f  // np.float32(1/sqrt(1+1e-3))

__device__ __forceinline__ float shflx(float v, int m) {
    return __shfl_xor(v, m, 64);
}

__device__ __forceinline__ int sel8i(int v0, int v1, int v2, int v3,
                                     int v4, int v5, int v6, int v7, int i) {
    int a0 = (i & 1) ? v1 : v0;
    int a1 = (i & 1) ? v3 : v2;
    int a2 = (i & 1) ? v5 : v4;
    int a3 = (i & 1) ? v7 : v6;
    int b0 = (i & 2) ? a1 : a0;
    int b1 = (i & 2) ? a3 : a2;
    return (i & 4) ? b1 : b0;
}

// fast tanh: clamp(+-9) then (e^2x-1)/(e^2x+1) via hw exp2 + rcp. (R6-R10: absmax 0.0)
__device__ __forceinline__ float tanh_fast(float x) {
    float y = fminf(fmaxf(x, -9.0f), 9.0f);
    float t = exp2f(y * 2.8853901817f);      // e^(2y)
    return (t - 1.0f) * __builtin_amdgcn_rcpf(t + 1.0f);
}

// liveness pin: forces all 4 components materialized in VGPRs at this point
#define PIN4(V) asm volatile("" : "+v"((V).x), "+v"((V).y), "+v"((V).z), "+v"((V).w))

// ---------------- Phase 1: gather + histogram (forced-depth bursts) ---------
template <bool PARTIAL>
__global__ __launch_bounds__(256, 4)
void drmm_hist(const int* __restrict__ doc,
               const int* __restrict__ query,
               const float* __restrict__ emb,
               float* __restrict__ hist_out)
{
    __shared__ float histw[4][8][32];   // [wave][q][bin(+2 pad)]
    __shared__ float qn_s[8];
    __shared__ float4 qlds[8][32];      // 8 q rows x 32 float4 = 4KB

    const int tid  = threadIdx.x;
    const int bid  = blockIdx.x;        // (bd, token-half)
    const int bd   = bid >> 1;
    const int b    = bid >> 5;          // bd >> 4
    const int wid  = tid >> 6;
    const int lane = tid & 63;

    // prefetch doc index immediately (hide its latency under setup)
    const int gtok = bid * 256 + tid;          // 0..262143
    const int idx  = doc[gtok];

    for (int i = tid; i < 4 * 8 * 32; i += 256) ((float*)histw)[i] = 0.0f;

    // wave-uniform query row indices (scalarized)
    const int* qrow = query + b * 8;
    const int qi0 = __builtin_amdgcn_readfirstlane(qrow[0]);
    const int qi1 = __builtin_amdgcn_readfirstlane(qrow[1]);
    const int qi2 = __builtin_amdgcn_readfirstlane(qrow[2]);
    const int qi3 = __builtin_amdgcn_readfirstlane(qrow[3]);
    const int qi4 = __builtin_amdgcn_readfirstlane(qrow[4]);
    const int qi5 = __builtin_amdgcn_readfirstlane(qrow[5]);
    const int qi6 = __builtin_amdgcn_readfirstlane(qrow[6]);
    const int qi7 = __builtin_amdgcn_readfirstlane(qrow[7]);

    // stage the 8 q rows into LDS: 256 threads x 1 float4 each
    {
        int q = tid >> 5;        // 0..7
        int c = tid & 31;        // 0..31
        int qis = sel8i(qi0, qi1, qi2, qi3, qi4, qi5, qi6, qi7, q);
        qlds[q][c] = *((const float4*)(emb + (size_t)qis * 128) + c);
    }
    __syncthreads();             // qlds + histw-zero complete

    const float4* rp = (const float4*)(emb + (size_t)idx * 128);

    float dd = 0.f;
    float dq0 = 0.f, dq1 = 0.f, dq2 = 0.f, dq3 = 0.f;
    float dq4 = 0.f, dq5 = 0.f, dq6 = 0.f, dq7 = 0.f;

    float4 A[8], B[8];
    // issue bursts 0 and 1 (lines 0,1) before the norm VALU work
#pragma unroll
    for (int p = 0; p < 8; ++p) A[p] = rp[p];
#pragma unroll
    for (int p = 0; p < 8; ++p) B[p] = rp[8 + p];

    // query norms: wave 0, from LDS (bit-identical values & op order to
    // the R5-R10 global-read version; absmax was 0.0). Runs while the row
    // bursts are in flight (LDS/VALU only).
    if (wid == 0) {
        int q = lane >> 3, jj = lane & 7;
        float s = 0.f;
#pragma unroll
        for (int c = 0; c < 4; ++c) {
            float4 x = qlds[q][jj * 4 + c];
            s = fmaf(x.x, x.x, s); s = fmaf(x.y, x.y, s);
            s = fmaf(x.z, x.z, s); s = fmaf(x.w, x.w, s);
        }
        s += shflx(s, 1); s += shflx(s, 2); s += shflx(s, 4);
        if (jj == 0) qn_s[q] = sqrtf(s);
    }

    // per-chunk compute: FMA sequence IDENTICAL to R7-R10 (bit-exact),
    // q values from LDS (lgkmcnt — independent of row vmcnt).
#define CSTEP(V, S) {                                                       \
        float4 v  = (V);                                                    \
        float4 a0 = qlds[0][S], a1 = qlds[1][S];                            \
        float4 a2 = qlds[2][S], a3 = qlds[3][S];                            \
        float4 a4 = qlds[4][S], a5 = qlds[5][S];                            \
        float4 a6 = qlds[6][S], a7 = qlds[7][S];                            \
        dd = fmaf(v.x, v.x, dd); dd = fmaf(v.y, v.y, dd);                   \
        dd = fmaf(v.z, v.z, dd); dd = fmaf(v.w, v.w, dd);                   \
        dq0 = fmaf(v.x, a0.x, dq0); dq0 = fmaf(v.y, a0.y, dq0);             \
        dq0 = fmaf(v.z, a0.z, dq0); dq0 = fmaf(v.w, a0.w, dq0);             \
        dq1 = fmaf(v.x, a1.x, dq1); dq1 = fmaf(v.y, a1.y, dq1);             \
        dq1 = fmaf(v.z, a1.z, dq1); dq1 = fmaf(v.w, a1.w, dq1);             \
        dq2 = fmaf(v.x, a2.x, dq2); dq2 = fmaf(v.y, a2.y, dq2);             \
        dq2 = fmaf(v.z, a2.z, dq2); dq2 = fmaf(v.w, a2.w, dq2);             \
        dq3 = fmaf(v.x, a3.x, dq3); dq3 = fmaf(v.y, a3.y, dq3);             \
        dq3 = fmaf(v.z, a3.z, dq3); dq3 = fmaf(v.w, a3.w, dq3);             \
        dq4 = fmaf(v.x, a4.x, dq4); dq4 = fmaf(v.y, a4.y, dq4);             \
        dq4 = fmaf(v.z, a4.z, dq4); dq4 = fmaf(v.w, a4.w, dq4);             \
        dq5 = fmaf(v.x, a5.x, dq5); dq5 = fmaf(v.y, a5.y, dq5);             \
        dq5 = fmaf(v.z, a5.z, dq5); dq5 = fmaf(v.w, a5.w, dq5);             \
        dq6 = fmaf(v.x, a6.x, dq6); dq6 = fmaf(v.y, a6.y, dq6);             \
        dq6 = fmaf(v.z, a6.z, dq6); dq6 = fmaf(v.w, a6.w, dq6);             \
        dq7 = fmaf(v.x, a7.x, dq7); dq7 = fmaf(v.y, a7.y, dq7);             \
        dq7 = fmaf(v.z, a7.z, dq7); dq7 = fmaf(v.w, a7.w, dq7);             \
    }

#pragma unroll
    for (int p = 0; p < 8; ++p) PIN4(A[p]);     // 16 loads issued, wait A only
#pragma unroll
    for (int p = 0; p < 8; ++p) CSTEP(A[p], p)  // compute chunks 0-7
#pragma unroll
    for (int p = 0; p < 8; ++p) A[p] = rp[16 + p];  // burst 2 -> A (line 2)
#pragma unroll
    for (int p = 0; p < 8; ++p) PIN4(B[p]);     // waits B (burst-2 in flight)
#pragma unroll
    for (int p = 0; p < 8; ++p) CSTEP(B[p], 8 + p)
#pragma unroll
    for (int p = 0; p < 8; ++p) B[p] = rp[24 + p];  // burst 3 -> B (line 3)
#pragma unroll
    for (int p = 0; p < 8; ++p) PIN4(A[p]);     // waits burst 2 (3 in flight)
#pragma unroll
    for (int p = 0; p < 8; ++p) CSTEP(A[p], 16 + p)
#pragma unroll
    for (int p = 0; p < 8; ++p) PIN4(B[p]);     // waits burst 3
#pragma unroll
    for (int p = 0; p < 8; ++p) CSTEP(B[p], 24 + p)
#undef CSTEP

    __syncthreads();             // qn_s ready for all waves

    const float dn = sqrtf(dd);
#define DOBIN(J, DQ) {                                                  \
        float sim = DQ / (dn * qn_s[J] + 1e-8f);                        \
        float u = (sim - 0.001f) / 0.999f * 30.0f;                      \
        int bin = (int)floorf(u);                                       \
        bin = bin < 0 ? 0 : (bin > 29 ? 29 : bin);                      \
        atomicAdd(&histw[wid][J][bin], 1.0f);                           \
    }
    DOBIN(0, dq0) DOBIN(1, dq1) DOBIN(2, dq2) DOBIN(3, dq3)
    DOBIN(4, dq4) DOBIN(5, dq5) DOBIN(6, dq6) DOBIN(7, dq7)
#undef DOBIN
    __syncthreads();

    // flush 8q x 30 bins (exact integer counts)
    if (tid < 240) {
        int q = tid / 30, k = tid - q * 30;
        float s = histw[0][q][k] + histw[1][q][k]
                + histw[2][q][k] + histw[3][q][k];
        if (PARTIAL) {
            hist_out[(size_t)bid * 240 + tid] = s;
        } else {
            atomicAdd(&hist_out[bd * 240 + tid], s);
        }
    }
}

// ---------------- Phase 2: gate softmax + MLP + output ----------------
template <bool PARTIAL>
__global__ __launch_bounds__(512, 3)
void drmm_mlp(const float* __restrict__ hist_g,
              const int* __restrict__ query,
              const float* __restrict__ idf,
              const float* __restrict__ w_gate,
              const float* __restrict__ g_in, const float* __restrict__ b_in,
              const float* __restrict__ W0, const float* __restrict__ b0,
              const float* __restrict__ g0, const float* __restrict__ be0,
              const float* __restrict__ W1, const float* __restrict__ b1,
              const float* __restrict__ g1, const float* __restrict__ be1,
              const float* __restrict__ W2, const float* __restrict__ b2,
              const float* __restrict__ g2, const float* __restrict__ be2,
              const float* __restrict__ W3, const float* __restrict__ b3,
              const float* __restrict__ g3, const float* __restrict__ be3,
              float* __restrict__ out)
{
    __shared__ float W1l[8192];   // 32KB: [k*64+j]
    __shared__ float xrow[8][30];
    __shared__ float h1s[8][128];
    __shared__ float h2s[8][64];
    __shared__ float h3s[8][32];
    __shared__ float gate_s[8];
    __shared__ float part[8];

    const int tid  = threadIdx.x;
    const int bd   = blockIdx.x;
    const int b    = bd >> 4;
    const int wid  = tid >> 6;
    const int lane = tid & 63;

    // bulk-stage W1 into LDS: 4 coalesced float4 per thread
#pragma unroll
    for (int i = 0; i < 4; ++i)
        ((float4*)W1l)[tid + i * 512] = ((const float4*)W1)[tid + i * 512];

    // Gate softmax: 8 parallel lanes (same op order as rounds 2-10).
    if (tid >= 504) {
        int q = tid - 504;
        float z = w_gate[q] * idf[query[b * 8 + q]];
        float m = z;
        m = fmaxf(m, shflx(m, 1)); m = fmaxf(m, shflx(m, 2)); m = fmaxf(m, shflx(m, 4));
        float e = expf(z - m);
        float s = e;
        s += shflx(s, 1); s += shflx(s, 2); s += shflx(s, 4);
        gate_s[q] = e / s;
    }

    if (tid < 240) {
        int q = tid / 30, k = tid - q * 30;
        float s;
        if (PARTIAL) {
            const float* hp = hist_g + (size_t)bd * 480 + tid;
            s = hp[0] + hp[240];  // exact int counts
        } else {
            s = hist_g[bd * 240 + tid];
        }
        xrow[q][k] = g_in[k] * (s * BN_INV) + b_in[k];
    }
    __syncthreads();

    // layer 1: 30 -> 128 (lane j computes outputs j and j+64); wave wid = q
    {
        float a0 = 0.f, a1 = 0.f;
#pragma unroll
        for (int k = 0; k < 30; ++k) {
            float xk = xrow[wid][k];
            a0 += xk * W0[k * 128 + lane];
            a1 += xk * W0[k * 128 + 64 + lane];
        }
        a0 += b0[lane]; a1 += b0[lane + 64];
        h1s[wid][lane]      = tanh_fast(g0[lane]      * (a0 * BN_INV) + be0[lane]);
        h1s[wid][lane + 64] = tanh_fast(g0[lane + 64] * (a1 * BN_INV) + be0[lane + 64]);
    }
    __syncthreads();

    // layer 2: 128 -> 64 (W1 from LDS; same k order -> bit-exact)
    {
        float a = 0.f;
#pragma unroll 16
        for (int k = 0; k < 128; ++k) a += h1s[wid][k] * W1l[k * 64 + lane];
        a += b1[lane];
        h2s[wid][lane] = tanh_fast(g1[lane] * (a * BN_INV) + be1[lane]);
    }
    __syncthreads();

    // layer 3: 64 -> 32 (written and read within wave wid — no barrier needed
    // before layer 4; same-wave LDS ordering is covered by lgkmcnt).
    if (lane < 32) {
        float a = 0.f;
#pragma unroll 8
        for (int k = 0; k < 64; ++k) a += h2s[wid][k] * W2[k * 32 + lane];
        a += b2[lane];
        h3s[wid][lane] = tanh_fast(g2[lane] * (a * BN_INV) + be2[lane]);
    }

    // layer 4: 32 -> 1, gate weighting (same wave as layer-3 writers)
    if (lane == 0) {
        float a = 0.f;
#pragma unroll
        for (int k = 0; k < 32; ++k) a += h3s[wid][k] * W3[k];
        a += b3[0];
        float y = tanh_fast(g3[0] * (a * BN_INV) + be3[0]);
        part[wid] = gate_s[wid] * y;
    }
    __syncthreads();

    if (tid == 0) {
        float s = 0.f;
#pragma unroll
        for (int q = 0; q < 8; ++q) s += part[q];
        out[bd] = s;
    }
}

extern "C" void kernel_launch(void* const* d_in, const int* in_sizes, int n_in,
                              void* d_out, int out_size, void* d_ws, size_t ws_size,
                              hipStream_t stream) {
    (void)in_sizes; (void)n_in; (void)out_size;
    const int*   doc    = (const int*)d_in[0];
    const int*   query  = (const int*)d_in[1];
    const float* emb    = (const float*)d_in[2];
    const float* idf    = (const float*)d_in[3];
    const float* w_gate = (const float*)d_in[4];
    const float* g_in   = (const float*)d_in[5];
    const float* b_in   = (const float*)d_in[6];
    const float* W0  = (const float*)d_in[7];
    const float* b0  = (const float*)d_in[8];
    const float* g0  = (const float*)d_in[9];
    const float* be0 = (const float*)d_in[10];
    const float* W1  = (const float*)d_in[11];
    const float* b1  = (const float*)d_in[12];
    const float* g1  = (const float*)d_in[13];
    const float* be1 = (const float*)d_in[14];
    const float* W2  = (const float*)d_in[15];
    const float* b2  = (const float*)d_in[16];
    const float* g2  = (const float*)d_in[17];
    const float* be2 = (const float*)d_in[18];
    const float* W3  = (const float*)d_in[19];
    const float* b3  = (const float*)d_in[20];
    const float* g3  = (const float*)d_in[21];
    const float* be3 = (const float*)d_in[22];

    float* hist_g = (float*)d_ws;
    const size_t need_partial = (size_t)1024 * 240 * sizeof(float); // 983 KB

    if (ws_size >= need_partial) {
        drmm_hist<true><<<dim3(1024), dim3(256), 0, stream>>>(doc, query, emb, hist_g);
        drmm_mlp<true><<<dim3(512), dim3(512), 0, stream>>>(
            hist_g, query, idf, w_gate, g_in, b_in,
            W0, b0, g0, be0, W1, b1, g1, be1,
            W2, b2, g2, be2, W3, b3, g3, be3, (float*)d_out);
    } else {
        hipMemsetAsync(hist_g, 0, 512 * 240 * sizeof(float), stream);
        drmm_hist<false><<<dim3(1024), dim3(256), 0, stream>>>(doc, query, emb, hist_g);
        drmm_mlp<false><<<dim3(512), dim3(512), 0, stream>>>(
            hist_g, query, idf, w_gate, g_in, b_in,
            W0, b0, g0, be0, W1, b1, g1, be1,
            W2, b2, g2, be2, W3, b3, g3, be3, (float*)d_out);
    }
}

// Round 12
// 47.980 us; speedup vs baseline: 1.0014x; 1.0014x over previous
//
#include <hip/hip_runtime.h>
#include <math.h>

// DRMM pipeline for MI355X (gfx950) — round 12: union of verified-good pieces.
// Phase 1: 4096 blocks x 512 thr (<=64 VGPR -> 32 waves/CU). 8-lane group owns
//   one token; instruction k loads the token's 128B line k WHOLE (R9's
//   occupancy-proof access); all 4 line-loads issued up-front with PIN forced
//   depth (R10/R11); q vectors from LDS broadcast (R11); 27-shuffle butterfly
//   + lane-j-bins-query-j (R9, absmax 0.0).
// Phase 2: MLP 30->128->64->32->1 + gate softmax + output. 512 blocks x 512 thr,
//   W1 bulk-staged to LDS (R11).
// B=32, D=16, L=512, Q=8, E=128, NB=30

#define BN_INV 0.99950037468777346f  // np.float32(1/sqrt(1+1e-3))

__device__ __forceinline__ float shflx(float v, int m) {
    return __shfl_xor(v, m, 64);
}

__device__ __forceinline__ int sel8i(int v0, int v1, int v2, int v3,
                                     int v4, int v5, int v6, int v7, int i) {
    int a0 = (i & 1) ? v1 : v0;
    int a1 = (i & 1) ? v3 : v2;
    int a2 = (i & 1) ? v5 : v4;
    int a3 = (i & 1) ? v7 : v6;
    int b0 = (i & 2) ? a1 : a0;
    int b1 = (i & 2) ? a3 : a2;
    return (i & 4) ? b1 : b0;
}

__device__ __forceinline__ float sel8f(float v0, float v1, float v2, float v3,
                                       float v4, float v5, float v6, float v7, int i) {
    float a0 = (i & 1) ? v1 : v0;
    float a1 = (i & 1) ? v3 : v2;
    float a2 = (i & 1) ? v5 : v4;
    float a3 = (i & 1) ? v7 : v6;
    float b0 = (i & 2) ? a1 : a0;
    float b1 = (i & 2) ? a3 : a2;
    return (i & 4) ? b1 : b0;
}

// fast tanh: clamp(+-9) then (e^2x-1)/(e^2x+1) via hw exp2 + rcp. (R6-R11: absmax 0.0)
__device__ __forceinline__ float tanh_fast(float x) {
    float y = fminf(fmaxf(x, -9.0f), 9.0f);
    float t = exp2f(y * 2.8853901817f);      // e^(2y)
    return (t - 1.0f) * __builtin_amdgcn_rcpf(t + 1.0f);
}

__device__ __forceinline__ float4 ld4(const float* base, int elem_off) {
    return *(const float4*)(base + elem_off);
}

// liveness pin: forces all 4 components materialized in VGPRs at this point
#define PIN4(V) asm volatile("" : "+v"((V).x), "+v"((V).y), "+v"((V).z), "+v"((V).w))

// ---------------- Phase 1: gather + histogram (8-lane coop, deep issue) -----
template <bool PARTIAL>
__global__ __launch_bounds__(512, 8)
void drmm_hist(const int* __restrict__ doc,
               const int* __restrict__ query,
               const float* __restrict__ emb,
               float* __restrict__ hist_out)
{
    __shared__ float histw[8][8][32];   // [wave][q][bin(+2 pad)] 8KB
    __shared__ float qn_s[8];
    __shared__ float4 qlds[8][32];      // 8 q rows x 32 float4 = 4KB

    const int tid  = threadIdx.x;
    const int bid  = blockIdx.x;        // 0..4095, 64 tokens each
    const int b    = bid >> 7;          // batch (128 blocks per batch)
    const int wid  = tid >> 6;          // wave 0..7
    const int lane = tid & 63;
    const int j    = tid & 7;           // lane in 8-lane group

    // doc index for this lane's group (8 lanes share one token)
    const int gtok = bid * 64 + (tid >> 3);       // 0..262143
    const int idx  = doc[gtok];

    for (int i = tid; i < 8 * 8 * 32; i += 512) ((float*)histw)[i] = 0.0f;

    // wave-uniform query row indices (scalarized)
    const int* qrow = query + b * 8;
    const int qi0 = __builtin_amdgcn_readfirstlane(qrow[0]);
    const int qi1 = __builtin_amdgcn_readfirstlane(qrow[1]);
    const int qi2 = __builtin_amdgcn_readfirstlane(qrow[2]);
    const int qi3 = __builtin_amdgcn_readfirstlane(qrow[3]);
    const int qi4 = __builtin_amdgcn_readfirstlane(qrow[4]);
    const int qi5 = __builtin_amdgcn_readfirstlane(qrow[5]);
    const int qi6 = __builtin_amdgcn_readfirstlane(qrow[6]);
    const int qi7 = __builtin_amdgcn_readfirstlane(qrow[7]);

    // stage the 8 q rows into LDS: threads 0..255, 1 float4 each
    if (tid < 256) {
        int q = tid >> 5;        // 0..7
        int c = tid & 31;        // 0..31
        int qis = sel8i(qi0, qi1, qi2, qi3, qi4, qi5, qi6, qi7, q);
        qlds[q][c] = *((const float4*)(emb + (size_t)qis * 128) + c);
    }
    __syncthreads();             // qlds + histw-zero complete

    // query norms: wave 0, from LDS (values & op order identical to R11,
    // which matched the R5-R10 global version bit-for-bit; absmax 0.0).
    if (wid == 0) {
        int q = lane >> 3, jj = lane & 7;
        float s = 0.f;
#pragma unroll
        for (int c = 0; c < 4; ++c) {
            float4 x = qlds[q][jj * 4 + c];
            s = fmaf(x.x, x.x, s); s = fmaf(x.y, x.y, s);
            s = fmaf(x.z, x.z, s); s = fmaf(x.w, x.w, s);
        }
        s += shflx(s, 1); s += shflx(s, 2); s += shflx(s, 4);
        if (jj == 0) qn_s[q] = sqrtf(s);
    }

    // ---- cooperative full-line row loads, all 4 issued before first use ----
    const float* rbase = emb + (size_t)idx * 128;
    const int eo = j * 4;                          // lane's element offset

    float4 A0 = ld4(rbase, eo);
    float4 A1 = ld4(rbase, eo + 32);
    float4 A2 = ld4(rbase, eo + 64);
    float4 A3 = ld4(rbase, eo + 96);

    float dd = 0.f;
    float dq0 = 0.f, dq1 = 0.f, dq2 = 0.f, dq3 = 0.f;
    float dq4 = 0.f, dq5 = 0.f, dq6 = 0.f, dq7 = 0.f;

    // KSTEP: FMA sequence identical to R9/R11 (bit-exact); q from LDS.
    // chunk index for KSTEP k is k*8 + j (lane j's float4 within line k).
#define KSTEP(V, K) {                                                       \
        const int S = (K) * 8 + j;                                          \
        float4 v  = (V);                                                    \
        float4 a0 = qlds[0][S], a1 = qlds[1][S];                            \
        float4 a2 = qlds[2][S], a3 = qlds[3][S];                            \
        float4 a4 = qlds[4][S], a5 = qlds[5][S];                            \
        float4 a6 = qlds[6][S], a7 = qlds[7][S];                            \
        dd = fmaf(v.x, v.x, dd); dd = fmaf(v.y, v.y, dd);                   \
        dd = fmaf(v.z, v.z, dd); dd = fmaf(v.w, v.w, dd);                   \
        dq0 = fmaf(v.x, a0.x, dq0); dq0 = fmaf(v.y, a0.y, dq0);             \
        dq0 = fmaf(v.z, a0.z, dq0); dq0 = fmaf(v.w, a0.w, dq0);             \
        dq1 = fmaf(v.x, a1.x, dq1); dq1 = fmaf(v.y, a1.y, dq1);             \
        dq1 = fmaf(v.z, a1.z, dq1); dq1 = fmaf(v.w, a1.w, dq1);             \
        dq2 = fmaf(v.x, a2.x, dq2); dq2 = fmaf(v.y, a2.y, dq2);             \
        dq2 = fmaf(v.z, a2.z, dq2); dq2 = fmaf(v.w, a2.w, dq2);             \
        dq3 = fmaf(v.x, a3.x, dq3); dq3 = fmaf(v.y, a3.y, dq3);             \
        dq3 = fmaf(v.z, a3.z, dq3); dq3 = fmaf(v.w, a3.w, dq3);             \
        dq4 = fmaf(v.x, a4.x, dq4); dq4 = fmaf(v.y, a4.y, dq4);             \
        dq4 = fmaf(v.z, a4.z, dq4); dq4 = fmaf(v.w, a4.w, dq4);             \
        dq5 = fmaf(v.x, a5.x, dq5); dq5 = fmaf(v.y, a5.y, dq5);             \
        dq5 = fmaf(v.z, a5.z, dq5); dq5 = fmaf(v.w, a5.w, dq5);             \
        dq6 = fmaf(v.x, a6.x, dq6); dq6 = fmaf(v.y, a6.y, dq6);             \
        dq6 = fmaf(v.z, a6.z, dq6); dq6 = fmaf(v.w, a6.w, dq6);             \
        dq7 = fmaf(v.x, a7.x, dq7); dq7 = fmaf(v.y, a7.y, dq7);             \
        dq7 = fmaf(v.z, a7.z, dq7); dq7 = fmaf(v.w, a7.w, dq7);             \
    }

    PIN4(A0); KSTEP(A0, 0)
    PIN4(A1); KSTEP(A1, 1)
    PIN4(A2); KSTEP(A2, 2)
    PIN4(A3); KSTEP(A3, 3)
#undef KSTEP

    // 3-round butterfly within each 8-lane group (order identical to R9)
#pragma unroll
    for (int off = 1; off <= 4; off <<= 1) {
        dd  += shflx(dd, off);
        dq0 += shflx(dq0, off); dq1 += shflx(dq1, off);
        dq2 += shflx(dq2, off); dq3 += shflx(dq3, off);
        dq4 += shflx(dq4, off); dq5 += shflx(dq5, off);
        dq6 += shflx(dq6, off); dq7 += shflx(dq7, off);
    }

    __syncthreads();             // qn_s ready for all waves

    // lane j bins query j (all 64 lanes active) — identical to R9
    {
        float dqj = sel8f(dq0, dq1, dq2, dq3, dq4, dq5, dq6, dq7, j);
        float sim = dqj / (sqrtf(dd) * qn_s[j] + 1e-8f);
        float u = (sim - 0.001f) / 0.999f * 30.0f;   // ref op order
        int bin = (int)floorf(u);
        bin = bin < 0 ? 0 : (bin > 29 ? 29 : bin);
        atomicAdd(&histw[wid][j][bin], 1.0f);
    }
    __syncthreads();

    // flush 8q x 30 bins (exact integer counts)
    if (tid < 240) {
        int q = tid / 30, k = tid - q * 30;
        float s = ((histw[0][q][k] + histw[1][q][k])
                 + (histw[2][q][k] + histw[3][q][k]))
                + ((histw[4][q][k] + histw[5][q][k])
                 + (histw[6][q][k] + histw[7][q][k]));
        if (PARTIAL) {
            hist_out[(size_t)bid * 240 + tid] = s;
        } else {
            atomicAdd(&hist_out[(bid >> 3) * 240 + tid], s);
        }
    }
}

// ---------------- Phase 2: gate softmax + MLP + output ----------------
template <bool PARTIAL>
__global__ __launch_bounds__(512, 3)
void drmm_mlp(const float* __restrict__ hist_g,
              const int* __restrict__ query,
              const float* __restrict__ idf,
              const float* __restrict__ w_gate,
              const float* __restrict__ g_in, const float* __restrict__ b_in,
              const float* __restrict__ W0, const float* __restrict__ b0,
              const float* __restrict__ g0, const float* __restrict__ be0,
              const float* __restrict__ W1, const float* __restrict__ b1,
              const float* __restrict__ g1, const float* __restrict__ be1,
              const float* __restrict__ W2, const float* __restrict__ b2,
              const float* __restrict__ g2, const float* __restrict__ be2,
              const float* __restrict__ W3, const float* __restrict__ b3,
              const float* __restrict__ g3, const float* __restrict__ be3,
              float* __restrict__ out)
{
    __shared__ float W1l[8192];   // 32KB: [k*64+j]
    __shared__ float xrow[8][30];
    __shared__ float h1s[8][128];
    __shared__ float h2s[8][64];
    __shared__ float h3s[8][32];
    __shared__ float gate_s[8];
    __shared__ float part[8];

    const int tid  = threadIdx.x;
    const int bd   = blockIdx.x;
    const int b    = bd >> 4;
    const int wid  = tid >> 6;
    const int lane = tid & 63;

    // bulk-stage W1 into LDS: 4 coalesced float4 per thread
#pragma unroll
    for (int i = 0; i < 4; ++i)
        ((float4*)W1l)[tid + i * 512] = ((const float4*)W1)[tid + i * 512];

    // Gate softmax: 8 parallel lanes (same op order as rounds 2-11).
    if (tid >= 504) {
        int q = tid - 504;
        float z = w_gate[q] * idf[query[b * 8 + q]];
        float m = z;
        m = fmaxf(m, shflx(m, 1)); m = fmaxf(m, shflx(m, 2)); m = fmaxf(m, shflx(m, 4));
        float e = expf(z - m);
        float s = e;
        s += shflx(s, 1); s += shflx(s, 2); s += shflx(s, 4);
        gate_s[q] = e / s;
    }

    if (tid < 240) {
        int q = tid / 30, k = tid - q * 30;
        float s;
        if (PARTIAL) {
            const float* hp = hist_g + (size_t)bd * 8 * 240 + tid;
            s = ((hp[0] + hp[240]) + (hp[480] + hp[720]))
              + ((hp[960] + hp[1200]) + (hp[1440] + hp[1680]));  // exact ints
        } else {
            s = hist_g[bd * 240 + tid];
        }
        xrow[q][k] = g_in[k] * (s * BN_INV) + b_in[k];
    }
    __syncthreads();

    // layer 1: 30 -> 128 (lane j computes outputs j and j+64); wave wid = q
    {
        float a0 = 0.f, a1 = 0.f;
#pragma unroll
        for (int k = 0; k < 30; ++k) {
            float xk = xrow[wid][k];
            a0 += xk * W0[k * 128 + lane];
            a1 += xk * W0[k * 128 + 64 + lane];
        }
        a0 += b0[lane]; a1 += b0[lane + 64];
        h1s[wid][lane]      = tanh_fast(g0[lane]      * (a0 * BN_INV) + be0[lane]);
        h1s[wid][lane + 64] = tanh_fast(g0[lane + 64] * (a1 * BN_INV) + be0[lane + 64]);
    }
    __syncthreads();

    // layer 2: 128 -> 64 (W1 from LDS; same k order -> bit-exact)
    {
        float a = 0.f;
#pragma unroll 16
        for (int k = 0; k < 128; ++k) a += h1s[wid][k] * W1l[k * 64 + lane];
        a += b1[lane];
        h2s[wid][lane] = tanh_fast(g1[lane] * (a * BN_INV) + be1[lane]);
    }
    __syncthreads();

    // layer 3: 64 -> 32 (same-wave LDS; no barrier needed before layer 4)
    if (lane < 32) {
        float a = 0.f;
#pragma unroll 8
        for (int k = 0; k < 64; ++k) a += h2s[wid][k] * W2[k * 32 + lane];
        a += b2[lane];
        h3s[wid][lane] = tanh_fast(g2[lane] * (a * BN_INV) + be2[lane]);
    }

    // layer 4: 32 -> 1, gate weighting (same wave as layer-3 writers)
    if (lane == 0) {
        float a = 0.f;
#pragma unroll
        for (int k = 0; k < 32; ++k) a += h3s[wid][k] * W3[k];
        a += b3[0];
        float y = tanh_fast(g3[0] * (a * BN_INV) + be3[0]);
        part[wid] = gate_s[wid] * y;
    }
    __syncthreads();

    if (tid == 0) {
        float s = 0.f;
#pragma unroll
        for (int q = 0; q < 8; ++q) s += part[q];
        out[bd] = s;
    }
}

extern "C" void kernel_launch(void* const* d_in, const int* in_sizes, int n_in,
                              void* d_out, int out_size, void* d_ws, size_t ws_size,
                              hipStream_t stream) {
    (void)in_sizes; (void)n_in; (void)out_size;
    const int*   doc    = (const int*)d_in[0];
    const int*   query  = (const int*)d_in[1];
    const float* emb    = (const float*)d_in[2];
    const float* idf    = (const float*)d_in[3];
    const float* w_gate = (const float*)d_in[4];
    const float* g_in   = (const float*)d_in[5];
    const float* b_in   = (const float*)d_in[6];
    const float* W0  = (const float*)d_in[7];
    const float* b0  = (const float*)d_in[8];
    const float* g0  = (const float*)d_in[9];
    const float* be0 = (const float*)d_in[10];
    const float* W1  = (const float*)d_in[11];
    const float* b1  = (const float*)d_in[12];
    const float* g1  = (const float*)d_in[13];
    const float* be1 = (const float*)d_in[14];
    const float* W2  = (const float*)d_in[15];
    const float* b2  = (const float*)d_in[16];
    const float* g2  = (const float*)d_in[17];
    const float* be2 = (const float*)d_in[18];
    const float* W3  = (const float*)d_in[19];
    const float* b3  = (const float*)d_in[20];
    const float* g3  = (const float*)d_in[21];
    const float* be3 = (const float*)d_in[22];

    float* hist_g = (float*)d_ws;
    const size_t need_partial = (size_t)4096 * 240 * sizeof(float); // 3.93 MB

    if (ws_size >= need_partial) {
        drmm_hist<true><<<dim3(4096), dim3(512), 0, stream>>>(doc, query, emb, hist_g);
        drmm_mlp<true><<<dim3(512), dim3(512), 0, stream>>>(
            hist_g, query, idf, w_gate, g_in, b_in,
            W0, b0, g0, be0, W1, b1, g1, be1,
            W2, b2, g2, be2, W3, b3, g3, be3, (float*)d_out);
    } else {
        hipMemsetAsync(hist_g, 0, 512 * 240 * sizeof(float), stream);
        drmm_hist<false><<<dim3(4096), dim3(512), 0, stream>>>(doc, query, emb, hist_g);
        drmm_mlp<false><<<dim3(512), dim3(512), 0, stream>>>(
            hist_g, query, idf, w_gate, g_in, b_in,
            W0, b0, g0, be0, W1, b1, g1, be1,
            W2, b2, g2, be2, W3, b3, g3, be3, (float*)d_out);
    }
}